// Round 2
// baseline (868.327 us; speedup 1.0000x reference)
//
#include <hip/hip_runtime.h>
#include <hip/hip_bf16.h>

using bf16 = __hip_bfloat16;
using u16  = unsigned short;
typedef __attribute__((ext_vector_type(8))) short s16x8;
typedef __attribute__((ext_vector_type(4))) float f32x4;

__device__ __forceinline__ float b2f(u16 u){
  union{unsigned u; float f;} c; c.u = ((unsigned)u)<<16; return c.f;
}
__device__ __forceinline__ u16 f2b(float f){
  union{float f; unsigned u;} c; c.f = f;
  unsigned r = (c.u + 0x7FFFu + ((c.u>>16)&1u)) >> 16;
  return (u16)r;
}

#define GLDS16(g, l_) __builtin_amdgcn_global_load_lds( \
    (const __attribute__((address_space(1))) unsigned int*)(g), \
    (__attribute__((address_space(3))) unsigned int*)(l_), 16, 0, 0)

// ---------------- GroupNorm: x[4,4096,512] fp32 -> h bf16, 32 groups of 16 ch ------
__global__ __launch_bounds__(512) void gn_kernel(const float* __restrict__ x,
    const float* __restrict__ gamma, const float* __restrict__ beta,
    bf16* __restrict__ h)
{
  const int b = blockIdx.x >> 5, g = blockIdx.x & 31;
  const int t = threadIdx.x;
  const size_t base = (size_t)b*4096*512 + (size_t)g*16;
  float sum = 0.f, sq = 0.f;
  for (int i = 0; i < 8; i++){
    const float* p = x + base + (size_t)(i*512 + t)*512;
    #pragma unroll
    for (int j = 0; j < 4; j++){
      f32x4 v = *(const f32x4*)(p + j*4);
      #pragma unroll
      for (int e = 0; e < 4; e++){ sum += v[e]; sq += v[e]*v[e]; }
    }
  }
  __shared__ float red[16];
  for (int o = 32; o > 0; o >>= 1){ sum += __shfl_xor(sum, o); sq += __shfl_xor(sq, o); }
  const int w = t >> 6, l = t & 63;
  if (l == 0){ red[w] = sum; red[8 + w] = sq; }
  __syncthreads();
  if (t == 0){
    float a = 0.f, bb = 0.f;
    for (int i = 0; i < 8; i++){ a += red[i]; bb += red[8 + i]; }
    red[0] = a; red[8] = bb;
  }
  __syncthreads();
  const float inv_n = 1.f/65536.f;
  const float mean = red[0]*inv_n;
  const float var  = red[8]*inv_n - mean*mean;
  const float rstd = rsqrtf(var + 1e-6f);
  float ga[16], be[16];
  #pragma unroll
  for (int j = 0; j < 16; j++){
    ga[j] = gamma[g*16 + j];
    be[j] = beta [g*16 + j];
  }
  u16* hp = (u16*)h;
  for (int i = 0; i < 8; i++){
    const float* p = x + base + (size_t)(i*512 + t)*512;
    u16* q = hp + base + (size_t)(i*512 + t)*512;
    s16x8 o0, o1;
    #pragma unroll
    for (int j = 0; j < 4; j++){
      f32x4 v = *(const f32x4*)(p + j*4);
      #pragma unroll
      for (int e = 0; e < 4; e++){
        int c = j*4 + e;
        u16 r = f2b((v[e] - mean)*rstd*ga[c] + be[c]);
        if (c < 8) o0[c] = (short)r; else o1[c - 8] = (short)r;
      }
    }
    *(s16x8*)q = o0; *(s16x8*)(q + 8) = o1;
  }
}

// ---------------- Tiled transpose+convert: in[R][C] -> out[C][R] (bf16) ------------
__device__ __forceinline__ float ldf(const float* p){ return *p; }
__device__ __forceinline__ float ldf(const u16* p){ return b2f(*p); }

template<typename T>
__global__ __launch_bounds__(256) void transpose_conv(const T* __restrict__ in,
    bf16* __restrict__ out, int R, int C)
{
  __shared__ float tile[64][65];
  const int tr = blockIdx.y * 64, tc = blockIdx.x * 64;
  const int t = threadIdx.x;
  #pragma unroll
  for (int i = 0; i < 16; i++){
    int idx = i*256 + t;
    int r = idx >> 6, c = idx & 63;
    tile[r][c] = ldf(in + (size_t)(tr + r)*C + tc + c);
  }
  __syncthreads();
  u16* op = (u16*)out;
  #pragma unroll
  for (int i = 0; i < 16; i++){
    int idx = i*256 + t;
    int r = idx >> 6, c = idx & 63;          // out row tc+r, out col tr+c
    op[(size_t)(tc + r)*R + tr + c] = f2b(tile[c][r]);
  }
}

// ---------------- GEMM (BT form): C[M,N] = A[M,K] @ Bt[N,K]^T ----------------------
// EPI bits: 1 = +bias[col] (fp32), 2 = *scale, 4 = +res[row*N+col] (fp32).
// OutT: bf16 (u16 store) or float.
template<int EPI, typename OutT>
__global__ __launch_bounds__(256) void gemm_bt(
    const bf16* __restrict__ A, const bf16* __restrict__ Bt, OutT* __restrict__ Cmat,
    int M, int N, int K, float scale,
    const float* __restrict__ bias, const float* __restrict__ res)
{
  __shared__ u16 As[128*64];
  __shared__ u16 Bs[128*64];
  const int t = threadIdx.x, l = t & 63, w = t >> 6;
  const int wr = w >> 1, wc = w & 1;
  const int m0 = blockIdx.y * 128, n0 = blockIdx.x * 128;
  const u16* Au  = (const u16*)A;
  const u16* Btu = (const u16*)Bt;

  f32x4 acc[4][4];
  #pragma unroll
  for (int m = 0; m < 4; m++)
    #pragma unroll
    for (int n = 0; n < 4; n++) acc[m][n] = (f32x4){0.f,0.f,0.f,0.f};

  const int srow = l >> 3, scol = (l & 7)*8;   // staging: lane -> (row-in-chunk, col)
  const int nkt = K >> 6;
  for (int kt = 0; kt < nkt; ++kt){
    const int k0 = kt << 6;
    #pragma unroll
    for (int j = 0; j < 4; j++){
      const int chunk = w*4 + j;               // 1KB chunk = 8 rows of 64 bf16
      const int row = chunk*8 + srow;
      GLDS16(Au  + (size_t)(m0 + row)*K + k0 + scol, &As[chunk*512]);
      GLDS16(Btu + (size_t)(n0 + row)*K + k0 + scol, &Bs[chunk*512]);
    }
    __syncthreads();
    #pragma unroll
    for (int kk = 0; kk < 2; kk++){
      s16x8 af[4], bff[4];
      #pragma unroll
      for (int m = 0; m < 4; m++)
        af[m]  = *(const s16x8*)&As[(wr*64 + m*16 + (l & 15))*64 + kk*32 + (l >> 4)*8];
      #pragma unroll
      for (int n = 0; n < 4; n++)
        bff[n] = *(const s16x8*)&Bs[(wc*64 + n*16 + (l & 15))*64 + kk*32 + (l >> 4)*8];
      #pragma unroll
      for (int m = 0; m < 4; m++)
        #pragma unroll
        for (int n = 0; n < 4; n++)
          acc[m][n] = __builtin_amdgcn_mfma_f32_16x16x32_bf16(af[m], bff[n], acc[m][n], 0, 0, 0);
    }
    __syncthreads();
  }
  // epilogue: D lane map (guide-verified): col = l&15, row = (l>>4)*4 + r
  const int lc = l & 15, lr4 = (l >> 4)*4;
  #pragma unroll
  for (int n = 0; n < 4; n++){
    const int col = n0 + wc*64 + n*16 + lc;
    const float bv = (EPI & 1) ? bias[col] : 0.f;
    #pragma unroll
    for (int m = 0; m < 4; m++){
      const int rowb = m0 + wr*64 + m*16 + lr4;
      #pragma unroll
      for (int r = 0; r < 4; r++){
        float v = acc[m][n][r];
        if (EPI & 2) v *= scale;
        v += bv;
        const size_t off = (size_t)(rowb + r)*N + col;
        if (EPI & 4) v += res[off];
        if constexpr (__is_same(OutT, float)) Cmat[off] = v;
        else ((u16*)Cmat)[off] = f2b(v);
      }
    }
  }
}

// ---------------- Row softmax over 4096 cols, in place (bf16) ----------------------
__global__ __launch_bounds__(256) void softmax_kernel(bf16* __restrict__ S)
{
  const int t = threadIdx.x;
  u16* p = (u16*)S + (size_t)blockIdx.x * 4096;
  float v[16];
  #pragma unroll
  for (int i = 0; i < 2; i++){
    s16x8 x = *(const s16x8*)(p + (size_t)(i*256 + t)*8);
    #pragma unroll
    for (int j = 0; j < 8; j++) v[i*8 + j] = b2f((u16)x[j]);
  }
  float mx = -1e30f;
  #pragma unroll
  for (int j = 0; j < 16; j++) mx = fmaxf(mx, v[j]);
  for (int o = 32; o > 0; o >>= 1) mx = fmaxf(mx, __shfl_xor(mx, o));
  __shared__ float red[8];
  const int w = t >> 6, l = t & 63;
  if (l == 0) red[w] = mx;
  __syncthreads();
  mx = fmaxf(fmaxf(red[0], red[1]), fmaxf(red[2], red[3]));
  float sum = 0.f;
  #pragma unroll
  for (int j = 0; j < 16; j++){ v[j] = __expf(v[j] - mx); sum += v[j]; }
  for (int o = 32; o > 0; o >>= 1) sum += __shfl_xor(sum, o);
  if (l == 0) red[4 + w] = sum;
  __syncthreads();
  const float inv = 1.f/(red[4] + red[5] + red[6] + red[7]);
  #pragma unroll
  for (int i = 0; i < 2; i++){
    s16x8 x;
    #pragma unroll
    for (int j = 0; j < 8; j++) x[j] = (short)f2b(v[i*8 + j]*inv);
    *(s16x8*)(p + (size_t)(i*256 + t)*8) = x;
  }
}

// -----------------------------------------------------------------------------------
extern "C" void kernel_launch(void* const* d_in, const int* in_sizes, int n_in,
                              void* d_out, int out_size, void* d_ws, size_t ws_size,
                              hipStream_t stream)
{
  (void)in_sizes; (void)n_in; (void)out_size; (void)ws_size;
  const float* x     = (const float*)d_in[0];
  const float* gamma = (const float*)d_in[1];
  const float* beta  = (const float*)d_in[2];
  const float* Wq = (const float*)d_in[3]; const float* bq = (const float*)d_in[4];
  const float* Wk = (const float*)d_in[5]; const float* bk = (const float*)d_in[6];
  const float* Wv = (const float*)d_in[7]; const float* bv = (const float*)d_in[8];
  const float* Wo = (const float*)d_in[9]; const float* bo = (const float*)d_in[10];
  float* out = (float*)d_out;

  const int B = 4, N = 4096, C = 512;
  char* p = (char*)d_ws;
  auto take = [&](size_t bytes){ void* r = (void*)p; p += (bytes + 255) & ~(size_t)255; return r; };
  bf16* h   = (bf16*)take((size_t)B*N*C*2);   // 16 MB (all batches)
  bf16* q   = (bf16*)take((size_t)N*C*2);     // 4 MB per-batch scratch
  bf16* k   = (bf16*)take((size_t)N*C*2);
  bf16* v   = (bf16*)take((size_t)N*C*2);
  bf16* vT  = (bf16*)take((size_t)N*C*2);
  bf16* ao  = (bf16*)take((size_t)N*C*2);
  bf16* S   = (bf16*)take((size_t)N*N*2);     // 32 MB per-batch scratch
  bf16* wqT = (bf16*)take((size_t)C*C*2);
  bf16* wkT = (bf16*)take((size_t)C*C*2);
  bf16* wvT = (bf16*)take((size_t)C*C*2);
  bf16* woT = (bf16*)take((size_t)C*C*2);     // total ~70 MB

  gn_kernel<<<dim3(B*32), dim3(512), 0, stream>>>(x, gamma, beta, h);

  transpose_conv<float><<<dim3(8, 8), 256, 0, stream>>>(Wq, wqT, C, C);
  transpose_conv<float><<<dim3(8, 8), 256, 0, stream>>>(Wk, wkT, C, C);
  transpose_conv<float><<<dim3(8, 8), 256, 0, stream>>>(Wv, wvT, C, C);
  transpose_conv<float><<<dim3(8, 8), 256, 0, stream>>>(Wo, woT, C, C);

  const float scl = 0.04419417382415922f;  // 512^-0.5
  const dim3 gProj(C/128, N/128);          // (4, 32)
  for (int b = 0; b < B; b++){
    const bf16* hb = h + (size_t)b*N*C;
    gemm_bt<1, bf16><<<gProj, 256, 0, stream>>>(hb, wqT, q, N, C, C, 1.f, bq, nullptr);
    gemm_bt<1, bf16><<<gProj, 256, 0, stream>>>(hb, wkT, k, N, C, C, 1.f, bk, nullptr);
    gemm_bt<1, bf16><<<gProj, 256, 0, stream>>>(hb, wvT, v, N, C, C, 1.f, bv, nullptr);
    transpose_conv<u16><<<dim3(C/64, N/64), 256, 0, stream>>>((const u16*)v, vT, N, C);
    gemm_bt<2, bf16><<<dim3(N/128, N/128), 256, 0, stream>>>(q, k, S, N, N, C, scl, nullptr, nullptr);
    softmax_kernel<<<dim3(N), 256, 0, stream>>>(S);
    gemm_bt<0, bf16><<<gProj, 256, 0, stream>>>(S, vT, ao, N, C, N, 1.f, nullptr, nullptr);
    gemm_bt<5, float><<<gProj, 256, 0, stream>>>(ao, woT, out + (size_t)b*N*C, N, C, C,
                                                 1.f, bo, x + (size_t)b*N*C);
  }
}

// Round 3
// 451.028 us; speedup vs baseline: 1.9252x; 1.9252x over previous
//
#include <hip/hip_runtime.h>
#include <hip/hip_bf16.h>

using bf16 = __hip_bfloat16;
using u16  = unsigned short;
typedef __attribute__((ext_vector_type(8))) short s16x8;
typedef __attribute__((ext_vector_type(4))) float f32x4;

__device__ __forceinline__ float b2f(u16 u){
  union{unsigned u; float f;} c; c.u = ((unsigned)u)<<16; return c.f;
}
__device__ __forceinline__ u16 f2b(float f){
  union{float f; unsigned u;} c; c.f = f;
  unsigned r = (c.u + 0x7FFFu + ((c.u>>16)&1u)) >> 16;
  return (u16)r;
}

#define GLDS16(g, l_) __builtin_amdgcn_global_load_lds( \
    (const __attribute__((address_space(1))) unsigned int*)(g), \
    (__attribute__((address_space(3))) unsigned int*)(l_), 16, 0, 0)

// ---------------- GroupNorm: x[4,4096,512] fp32 -> h bf16, 32 groups of 16 ch ------
__global__ __launch_bounds__(512) void gn_kernel(const float* __restrict__ x,
    const float* __restrict__ gamma, const float* __restrict__ beta,
    bf16* __restrict__ h)
{
  const int b = blockIdx.x >> 5, g = blockIdx.x & 31;
  const int t = threadIdx.x;
  const size_t base = (size_t)b*4096*512 + (size_t)g*16;
  float sum = 0.f, sq = 0.f;
  for (int i = 0; i < 8; i++){
    const float* p = x + base + (size_t)(i*512 + t)*512;
    #pragma unroll
    for (int j = 0; j < 4; j++){
      f32x4 v = *(const f32x4*)(p + j*4);
      #pragma unroll
      for (int e = 0; e < 4; e++){ sum += v[e]; sq += v[e]*v[e]; }
    }
  }
  __shared__ float red[16];
  for (int o = 32; o > 0; o >>= 1){ sum += __shfl_xor(sum, o); sq += __shfl_xor(sq, o); }
  const int w = t >> 6, l = t & 63;
  if (l == 0){ red[w] = sum; red[8 + w] = sq; }
  __syncthreads();
  if (t == 0){
    float a = 0.f, bb = 0.f;
    for (int i = 0; i < 8; i++){ a += red[i]; bb += red[8 + i]; }
    red[0] = a; red[8] = bb;
  }
  __syncthreads();
  const float inv_n = 1.f/65536.f;
  const float mean = red[0]*inv_n;
  const float var  = red[8]*inv_n - mean*mean;
  const float rstd = rsqrtf(var + 1e-6f);
  float ga[16], be[16];
  #pragma unroll
  for (int j = 0; j < 16; j++){
    ga[j] = gamma[g*16 + j];
    be[j] = beta [g*16 + j];
  }
  u16* hp = (u16*)h;
  for (int i = 0; i < 8; i++){
    const float* p = x + base + (size_t)(i*512 + t)*512;
    u16* q = hp + base + (size_t)(i*512 + t)*512;
    s16x8 o0, o1;
    #pragma unroll
    for (int j = 0; j < 4; j++){
      f32x4 v = *(const f32x4*)(p + j*4);
      #pragma unroll
      for (int e = 0; e < 4; e++){
        int c = j*4 + e;
        u16 r = f2b((v[e] - mean)*rstd*ga[c] + be[c]);
        if (c < 8) o0[c] = (short)r; else o1[c - 8] = (short)r;
      }
    }
    *(s16x8*)q = o0; *(s16x8*)(q + 8) = o1;
  }
}

// ---------------- Weight transpose: 4x [512,512] fp32 -> bf16 transposed -----------
struct W4 { const float* p[4]; };
__global__ __launch_bounds__(256) void transpose_w4(W4 srcs, bf16* __restrict__ dst)
{
  __shared__ float tile[64][65];
  const float* in = srcs.p[blockIdx.z];
  u16* out = (u16*)dst + (size_t)blockIdx.z*512*512;
  const int tr = blockIdx.y*64, tc = blockIdx.x*64;
  const int t = threadIdx.x;
  #pragma unroll
  for (int i = 0; i < 16; i++){
    int idx = i*256 + t, r = idx >> 6, c = idx & 63;
    tile[r][c] = in[(size_t)(tr + r)*512 + tc + c];
  }
  __syncthreads();
  #pragma unroll
  for (int i = 0; i < 16; i++){
    int idx = i*256 + t, r = idx >> 6, c = idx & 63;
    out[(size_t)(tc + r)*512 + tr + c] = f2b(tile[c][r]);
  }
}

// ---------------- V transpose: qkv[:,1024:1536] (bf16, ld 1536) -> vT[b][512][4096]
__global__ __launch_bounds__(256) void transpose_v(const u16* __restrict__ qkv,
    bf16* __restrict__ vT)
{
  __shared__ u16 tile[64][72];
  const u16* in = qkv + 1024 + (size_t)blockIdx.z*4096*1536;
  u16* out = (u16*)vT + (size_t)blockIdx.z*512*4096;
  const int tr = blockIdx.y*64, tc = blockIdx.x*64;   // tr: n rows, tc: c cols
  const int t = threadIdx.x;
  #pragma unroll
  for (int i = 0; i < 16; i++){
    int idx = i*256 + t, r = idx >> 6, c = idx & 63;
    tile[r][c] = in[(size_t)(tr + r)*1536 + tc + c];
  }
  __syncthreads();
  #pragma unroll
  for (int i = 0; i < 16; i++){
    int idx = i*256 + t, r = idx >> 6, c = idx & 63;
    out[(size_t)(tc + r)*4096 + tr + c] = tile[c][r];
  }
}

// ---------------- GEMM (BT form): C[.,n] = A[.,K] @ Bt[n,K]^T ----------------------
// EPI bits: 1 = +b0[col], 2 = *scale, 4 = +res[row*ldc+col] (fp32), 8 = QKV 3-way bias.
// T2 swizzle: linear LDS dest via global_load_lds with pre-swizzled SOURCE slot,
// matching XOR on ds_read byte address (both-sides-or-neither, rule #21).
template<int EPI, typename OutT>
__global__ __launch_bounds__(256) void gemm_bt(
    const u16* __restrict__ A, int lda, long sA,
    const u16* __restrict__ Bt, int ldb, long sB,
    OutT* __restrict__ Cmat, int ldc, long sC,
    int K, float scale,
    const float* __restrict__ b0, const float* __restrict__ b1,
    const float* __restrict__ b2, const float* __restrict__ res)
{
  __shared__ u16 As[128*64];
  __shared__ u16 Bs[128*64];
  const int t = threadIdx.x, l = t & 63, w = t >> 6;
  const int wr = w >> 1, wc = w & 1;
  const int m0 = blockIdx.y * 128, n0 = blockIdx.x * 128;
  const u16* Au  = A  + (size_t)blockIdx.z * sA;
  const u16* Btu = Bt + (size_t)blockIdx.z * sB;

  f32x4 acc[4][4];
  #pragma unroll
  for (int m = 0; m < 4; m++)
    #pragma unroll
    for (int n = 0; n < 4; n++) acc[m][n] = (f32x4){0.f,0.f,0.f,0.f};

  const int srow = l >> 3;
  const int scol = ((l & 7) ^ srow) * 8;       // swizzled source slot (T2 write side)
  const int xorv = (l & 7) << 4;               // read-side XOR: row&7 == l&7 for our rows
  const int nkt = K >> 6;
  for (int kt = 0; kt < nkt; ++kt){
    const int k0 = kt << 6;
    #pragma unroll
    for (int j = 0; j < 4; j++){
      const int chunk = w*4 + j;               // 1KB chunk = 8 rows of 64 bf16
      const int row = chunk*8 + srow;
      GLDS16(Au  + (size_t)(m0 + row)*lda + k0 + scol, &As[chunk*512]);
      GLDS16(Btu + (size_t)(n0 + row)*ldb + k0 + scol, &Bs[chunk*512]);
    }
    __syncthreads();
    #pragma unroll
    for (int kk = 0; kk < 2; kk++){
      const int kbyte = (kk*64 + (l >> 4)*16) ^ xorv;
      s16x8 af[4], bff[4];
      #pragma unroll
      for (int m = 0; m < 4; m++)
        af[m]  = *(const s16x8*)((const char*)As + (wr*64 + m*16 + (l & 15))*128 + kbyte);
      #pragma unroll
      for (int n = 0; n < 4; n++)
        bff[n] = *(const s16x8*)((const char*)Bs + (wc*64 + n*16 + (l & 15))*128 + kbyte);
      #pragma unroll
      for (int m = 0; m < 4; m++)
        #pragma unroll
        for (int n = 0; n < 4; n++)
          acc[m][n] = __builtin_amdgcn_mfma_f32_16x16x32_bf16(af[m], bff[n], acc[m][n], 0, 0, 0);
    }
    __syncthreads();
  }
  // epilogue: D lane map: col = l&15, row = (l>>4)*4 + r
  const int lc = l & 15, lr4 = (l >> 4)*4;
  OutT* Cz = Cmat + (size_t)blockIdx.z * sC;
  #pragma unroll
  for (int n = 0; n < 4; n++){
    const int col = n0 + wc*64 + n*16 + lc;
    float bv = 0.f;
    if (EPI & 8){
      const float* bp = (col < 512) ? b0 : (col < 1024 ? b1 : b2);
      bv = bp[col & 511];
    } else if (EPI & 1){
      bv = b0[col];
    }
    #pragma unroll
    for (int m = 0; m < 4; m++){
      const int rowb = m0 + wr*64 + m*16 + lr4;
      #pragma unroll
      for (int r = 0; r < 4; r++){
        float v = acc[m][n][r];
        if (EPI & 2) v *= scale;
        v += bv;
        const size_t off = (size_t)(rowb + r)*ldc + col;
        if (EPI & 4) v += res[off];
        if constexpr (__is_same(OutT, float)) Cz[off] = v;
        else ((u16*)Cz)[off] = f2b(v);
      }
    }
  }
}

// ---------------- Row softmax over 4096 cols, in place (bf16) ----------------------
__global__ __launch_bounds__(256) void softmax_kernel(bf16* __restrict__ S)
{
  const int t = threadIdx.x;
  u16* p = (u16*)S + ((size_t)blockIdx.y*4096 + blockIdx.x)*4096;
  float v[16];
  #pragma unroll
  for (int i = 0; i < 2; i++){
    s16x8 x = *(const s16x8*)(p + (size_t)(i*256 + t)*8);
    #pragma unroll
    for (int j = 0; j < 8; j++) v[i*8 + j] = b2f((u16)x[j]);
  }
  float mx = -1e30f;
  #pragma unroll
  for (int j = 0; j < 16; j++) mx = fmaxf(mx, v[j]);
  for (int o = 32; o > 0; o >>= 1) mx = fmaxf(mx, __shfl_xor(mx, o));
  __shared__ float red[8];
  const int w = t >> 6, l = t & 63;
  if (l == 0) red[w] = mx;
  __syncthreads();
  mx = fmaxf(fmaxf(red[0], red[1]), fmaxf(red[2], red[3]));
  float sum = 0.f;
  #pragma unroll
  for (int j = 0; j < 16; j++){ v[j] = __expf(v[j] - mx); sum += v[j]; }
  for (int o = 32; o > 0; o >>= 1) sum += __shfl_xor(sum, o);
  if (l == 0) red[4 + w] = sum;
  __syncthreads();
  const float inv = 1.f/(red[4] + red[5] + red[6] + red[7]);
  #pragma unroll
  for (int i = 0; i < 2; i++){
    s16x8 x;
    #pragma unroll
    for (int j = 0; j < 8; j++) x[j] = (short)f2b(v[i*8 + j]*inv);
    *(s16x8*)(p + (size_t)(i*256 + t)*8) = x;
  }
}

// -----------------------------------------------------------------------------------
extern "C" void kernel_launch(void* const* d_in, const int* in_sizes, int n_in,
                              void* d_out, int out_size, void* d_ws, size_t ws_size,
                              hipStream_t stream)
{
  (void)in_sizes; (void)n_in; (void)out_size;
  const float* x     = (const float*)d_in[0];
  const float* gamma = (const float*)d_in[1];
  const float* beta  = (const float*)d_in[2];
  const float* Wq = (const float*)d_in[3]; const float* bq = (const float*)d_in[4];
  const float* Wk = (const float*)d_in[5]; const float* bk = (const float*)d_in[6];
  const float* Wv = (const float*)d_in[7]; const float* bv = (const float*)d_in[8];
  const float* Wo = (const float*)d_in[9]; const float* bo = (const float*)d_in[10];
  float* out = (float*)d_out;

  const int B = 4, N = 4096, C = 512;
  const long NC = (long)N*C;
  const float scl = 0.04419417382415922f;  // 512^-0.5

  // ---- workspace layout ----
  char* p0 = (char*)d_ws;
  auto align = [](size_t b){ return (b + 255) & ~(size_t)255; };
  const size_t sz_h   = align((size_t)B*NC*2);
  const size_t sz_w   = align((size_t)4*C*C*2);
  const size_t sz_qkvF= align((size_t)B*N*1536*2);
  const size_t sz_vTF = align((size_t)B*NC*2);
  const size_t sz_aoF = align((size_t)B*NC*2);
  const size_t sz_SF  = align((size_t)B*N*N*2);
  const size_t need_full = sz_h + sz_w + sz_qkvF + sz_vTF + sz_aoF + sz_SF;

  bf16* h    = (bf16*)p0;
  bf16* wAll = (bf16*)(p0 + sz_h);            // rows: wq^T | wk^T | wv^T | wo^T
  char* pv   = p0 + sz_h + sz_w;

  // ---- common prologue ----
  gn_kernel<<<dim3(B*32), dim3(512), 0, stream>>>(x, gamma, beta, h);
  W4 ws4; ws4.p[0] = Wq; ws4.p[1] = Wk; ws4.p[2] = Wv; ws4.p[3] = Wo;
  transpose_w4<<<dim3(8, 8, 4), 256, 0, stream>>>(ws4, wAll);
  bf16* woT = wAll + (size_t)3*C*C;

  if (ws_size >= need_full){
    // ---- fully batched path ----
    bf16* qkv = (bf16*)pv;
    bf16* vT  = (bf16*)(pv + sz_qkvF);
    bf16* ao  = (bf16*)(pv + sz_qkvF + sz_vTF);
    bf16* S   = (bf16*)(pv + sz_qkvF + sz_vTF + sz_aoF);

    gemm_bt<8, bf16><<<dim3(12, 128, 1), 256, 0, stream>>>(
        (const u16*)h, C, 0, (const u16*)wAll, C, 0, qkv, 1536, 0,
        C, 1.f, bq, bk, bv, nullptr);
    transpose_v<<<dim3(8, 64, B), 256, 0, stream>>>((const u16*)qkv, vT);
    gemm_bt<2, bf16><<<dim3(32, 32, B), 256, 0, stream>>>(
        (const u16*)qkv, 1536, (long)N*1536, (const u16*)qkv + 512, 1536, (long)N*1536,
        S, N, (long)N*N, C, scl, nullptr, nullptr, nullptr, nullptr);
    softmax_kernel<<<dim3(N, B), 256, 0, stream>>>(S);
    gemm_bt<0, bf16><<<dim3(4, 32, B), 256, 0, stream>>>(
        (const u16*)S, N, (long)N*N, (const u16*)vT, N, NC,
        ao, C, NC, N, 1.f, nullptr, nullptr, nullptr, nullptr);
    gemm_bt<5, float><<<dim3(4, 128, 1), 256, 0, stream>>>(
        (const u16*)ao, C, 0, (const u16*)woT, C, 0, out, C, 0,
        C, 1.f, bo, nullptr, nullptr, x);
  } else {
    // ---- per-batch fallback (~73 MB) ----
    const size_t sz_qkv1 = align((size_t)N*1536*2);
    const size_t sz_vT1  = align((size_t)NC*2);
    const size_t sz_ao1  = align((size_t)NC*2);
    bf16* qkv = (bf16*)pv;
    bf16* vT  = (bf16*)(pv + sz_qkv1);
    bf16* ao  = (bf16*)(pv + sz_qkv1 + sz_vT1);
    bf16* S   = (bf16*)(pv + sz_qkv1 + sz_vT1 + sz_ao1);
    for (int b = 0; b < B; b++){
      const u16* hb = (const u16*)h + (size_t)b*NC;
      gemm_bt<8, bf16><<<dim3(12, 32, 1), 256, 0, stream>>>(
          hb, C, 0, (const u16*)wAll, C, 0, qkv, 1536, 0,
          C, 1.f, bq, bk, bv, nullptr);
      transpose_v<<<dim3(8, 64, 1), 256, 0, stream>>>((const u16*)qkv, vT);
      gemm_bt<2, bf16><<<dim3(32, 32, 1), 256, 0, stream>>>(
          (const u16*)qkv, 1536, 0, (const u16*)qkv + 512, 1536, 0,
          S, N, 0, C, scl, nullptr, nullptr, nullptr, nullptr);
      softmax_kernel<<<dim3(N, 1), 256, 0, stream>>>(S);
      gemm_bt<0, bf16><<<dim3(4, 32, 1), 256, 0, stream>>>(
          (const u16*)S, N, 0, (const u16*)vT, N, 0,
          ao, C, 0, N, 1.f, nullptr, nullptr, nullptr, nullptr);
      gemm_bt<5, float><<<dim3(4, 32, 1), 256, 0, stream>>>(
          (const u16*)ao, C, 0, (const u16*)woT, C, 0, out + (size_t)b*NC, C, 0,
          C, 1.f, bo, nullptr, nullptr, x + (size_t)b*NC);
    }
  }
}